// Round 1
// baseline (171.604 us; speedup 1.0000x reference)
//
#include <hip/hip_runtime.h>
#include <math.h>

#define HH 1024
#define WW 1024
#define RR 8192
#define EPSF 1e-10f

// ws layout (bytes):
//   [0,          8388608)  rowpref -> becomes integral image C in-place (1024*1024 f64)
//   [8388608,    8650752)  bsum (32*1024 f64) column chunk sums
//   [8650752,    8683520)  iou (8192 f32)
//   [8683520,    8683528)  acc (1 f64)
#define OFF_BSUM  8388608
#define OFF_IOU   8650752
#define OFF_ACC   8683520

__device__ __forceinline__ double sigm(float a, float b) {
    // softmax over 2 channels, channel 1: sigmoid(b - a) = 1/(1+exp(a-b))
    return 1.0 / (1.0 + (double)expf(a - b));
}

// Kernel A: per-row prefix sum of sigmoid(seg1-seg0), fp64 out. One block per row.
__global__ void row_scan(const float* __restrict__ seg, double* __restrict__ rowpref) {
    const int h = blockIdx.x;
    const int t = threadIdx.x;
    const float4* s0 = (const float4*)(seg + (size_t)h * WW);
    const float4* s1 = (const float4*)(seg + (size_t)(HH * WW) + (size_t)h * WW);
    float4 a = s0[t];
    float4 b = s1[t];
    double p0 = sigm(a.x, b.x);
    double p1 = p0 + sigm(a.y, b.y);
    double p2 = p1 + sigm(a.z, b.z);
    double p3 = p2 + sigm(a.w, b.w);

    // inclusive scan of per-thread totals across the block
    double tsum = p3;
    const int lane = t & 63, wid = t >> 6;
    #pragma unroll
    for (int off = 1; off < 64; off <<= 1) {
        double n = __shfl_up(tsum, off, 64);
        if (lane >= off) tsum += n;
    }
    __shared__ double wsum[4];
    if (lane == 63) wsum[wid] = tsum;
    __syncthreads();
    double woff = 0.0;
    for (int k = 0; k < wid; ++k) woff += wsum[k];
    const double excl = woff + tsum - p3;   // exclusive prefix for this thread

    double* out = rowpref + (size_t)h * WW + 4 * t;
    out[0] = excl + p0;
    out[1] = excl + p1;
    out[2] = excl + p2;
    out[3] = excl + p3;
}

// Kernel B: per-(32-row chunk, column) partial sums. grid (4, 32), block 256.
__global__ void col_partial(const double* __restrict__ rowpref, double* __restrict__ bsum) {
    const int w = blockIdx.x * 256 + threadIdx.x;
    const int chunk = blockIdx.y;
    const int r0 = chunk * 32;
    double acc = 0.0;
    #pragma unroll 4
    for (int r = r0; r < r0 + 32; ++r) acc += rowpref[(size_t)r * WW + w];
    bsum[chunk * WW + w] = acc;
}

// Kernel C: column scan using chunk offsets; rowpref becomes the integral image in place.
__global__ void col_scan(double* __restrict__ rowpref, const double* __restrict__ bsum) {
    const int w = blockIdx.x * 256 + threadIdx.x;
    const int chunk = blockIdx.y;
    double acc = 0.0;
    for (int k = 0; k < chunk; ++k) acc += bsum[k * WW + w];
    const int r0 = chunk * 32;
    for (int r = r0; r < r0 + 32; ++r) {
        acc += rowpref[(size_t)r * WW + w];
        rowpref[(size_t)r * WW + w] = acc;
    }
}

// Kernel D: per-box iou. P(y,x) = (y>0 && x>0) ? C[y-1][x-1] : 0
__global__ void box_iou(const int* __restrict__ ssw, const double* __restrict__ C,
                        float* __restrict__ iou) {
    const int r = blockIdx.x * 256 + threadIdx.x;
    const int* b = ssw + r * 5;
    const int x1 = b[1], y1 = b[2], x2 = b[3], y2 = b[4];
    // x2,y2 >= 1 always (w,h >= 1)
    double p22 = C[(size_t)(y2 - 1) * WW + (x2 - 1)];
    double p12 = (y1 > 0) ? C[(size_t)(y1 - 1) * WW + (x2 - 1)] : 0.0;
    double p21 = (x1 > 0) ? C[(size_t)(y2 - 1) * WW + (x1 - 1)] : 0.0;
    double p11 = (y1 > 0 && x1 > 0) ? C[(size_t)(y1 - 1) * WW + (x1 - 1)] : 0.0;
    double sums = p22 - p12 - p21 + p11;
    double area = (double)((y2 - y1) * (x2 - x1));
    iou[r] = (float)(sums / area);
}

// Kernel E: pairwise loss, grid (R/256, R/1024) = (32, 8), block 256.
__global__ void pair_loss(const float* __restrict__ iou, const float* __restrict__ score,
                          double* __restrict__ acc) {
    __shared__ float iou_s[1024];
    __shared__ float sc_s[1024];
    const int t = threadIdx.x;
    const int i = blockIdx.x * 256 + t;
    const int j0 = blockIdx.y * 1024;
    for (int k = t; k < 1024; k += 256) {
        iou_s[k] = iou[j0 + k];
        sc_s[k]  = score[j0 + k];
    }
    __syncthreads();
    const float ii = iou[i];
    const float si = score[i];
    float accf = 0.0f;
    #pragma unroll 8
    for (int j = 0; j < 1024; ++j) {
        float dio = ii - iou_s[j];
        float a = sqrtf(dio * dio + EPSF);
        float dsc = si - sc_s[j];
        float b = sqrtf(dsc * dsc + EPSF);
        float d = a - b;
        accf += d * d;
    }
    double v = (double)accf;
    #pragma unroll
    for (int off = 32; off; off >>= 1) v += __shfl_down(v, off, 64);
    __shared__ double wred[4];
    const int lane = t & 63, wid = t >> 6;
    if (lane == 0) wred[wid] = v;
    __syncthreads();
    if (t == 0) atomicAdd(acc, wred[0] + wred[1] + wred[2] + wred[3]);
}

__global__ void finalize(const double* __restrict__ acc, float* __restrict__ out) {
    out[0] = (float)(acc[0] * (1.0 / ((double)RR * (double)RR)));
}

extern "C" void kernel_launch(void* const* d_in, const int* in_sizes, int n_in,
                              void* d_out, int out_size, void* d_ws, size_t ws_size,
                              hipStream_t stream) {
    const int*   ssw   = (const int*)d_in[0];
    const float* seg   = (const float*)d_in[1];
    const float* score = (const float*)d_in[2];

    double* rowpref = (double*)d_ws;
    double* bsum    = (double*)((char*)d_ws + OFF_BSUM);
    float*  iou     = (float*)((char*)d_ws + OFF_IOU);
    double* acc     = (double*)((char*)d_ws + OFF_ACC);

    hipMemsetAsync(acc, 0, sizeof(double), stream);

    row_scan<<<HH, 256, 0, stream>>>(seg, rowpref);
    col_partial<<<dim3(4, 32), 256, 0, stream>>>(rowpref, bsum);
    col_scan<<<dim3(4, 32), 256, 0, stream>>>(rowpref, bsum);
    box_iou<<<RR / 256, 256, 0, stream>>>(ssw, rowpref, iou);
    pair_loss<<<dim3(RR / 256, RR / 1024), 256, 0, stream>>>(iou, score, acc);
    finalize<<<1, 1, 0, stream>>>(acc, (float*)d_out);
}

// Round 2
// 110.452 us; speedup vs baseline: 1.5537x; 1.5537x over previous
//
#include <hip/hip_runtime.h>
#include <math.h>

#define HH 1024
#define WW 1024
#define RR 8192
#define EPSF 1e-10f
#define EPSD 1e-10

// ws layout (bytes):
//   [0,          8388608)  rowpref -> becomes integral image C in-place (1024*1024 f64)
//   [8388608,    8650752)  bsum (32*1024 f64) column chunk sums
//   [8650752,    8683520)  iou (8192 f32)
//   [8683520,    8683560)  stats: 5 f64  {Su, Su2, Ss, Ss2, Sab}
#define OFF_BSUM  8388608
#define OFF_IOU   8650752
#define OFF_STAT  8683520

__device__ __forceinline__ double sigm(float a, float b) {
    // softmax over 2 channels, channel 1: 1/(1+exp(a-b))
    return 1.0 / (1.0 + (double)expf(a - b));
}

// Kernel A: per-row prefix sum of sigmoid(seg1-seg0), fp64 out. One block per row.
__global__ void row_scan(const float* __restrict__ seg, double* __restrict__ rowpref) {
    const int h = blockIdx.x;
    const int t = threadIdx.x;
    const float4* s0 = (const float4*)(seg + (size_t)h * WW);
    const float4* s1 = (const float4*)(seg + (size_t)(HH * WW) + (size_t)h * WW);
    float4 a = s0[t];
    float4 b = s1[t];
    double p0 = sigm(a.x, b.x);
    double p1 = p0 + sigm(a.y, b.y);
    double p2 = p1 + sigm(a.z, b.z);
    double p3 = p2 + sigm(a.w, b.w);

    double tsum = p3;
    const int lane = t & 63, wid = t >> 6;
    #pragma unroll
    for (int off = 1; off < 64; off <<= 1) {
        double n = __shfl_up(tsum, off, 64);
        if (lane >= off) tsum += n;
    }
    __shared__ double wsum[4];
    if (lane == 63) wsum[wid] = tsum;
    __syncthreads();
    double woff = 0.0;
    for (int k = 0; k < wid; ++k) woff += wsum[k];
    const double excl = woff + tsum - p3;

    double* out = rowpref + (size_t)h * WW + 4 * t;
    out[0] = excl + p0;
    out[1] = excl + p1;
    out[2] = excl + p2;
    out[3] = excl + p3;
}

// Kernel B: per-(32-row chunk, column) partial sums. grid (4, 32), block 256.
__global__ void col_partial(const double* __restrict__ rowpref, double* __restrict__ bsum) {
    const int w = blockIdx.x * 256 + threadIdx.x;
    const int chunk = blockIdx.y;
    const int r0 = chunk * 32;
    double acc = 0.0;
    #pragma unroll 4
    for (int r = r0; r < r0 + 32; ++r) acc += rowpref[(size_t)r * WW + w];
    bsum[chunk * WW + w] = acc;
}

// Kernel C: column scan; rowpref becomes the integral image in place.
// Also zeroes the 5 stats accumulators (runs before box_stats on the stream).
__global__ void col_scan(double* __restrict__ rowpref, const double* __restrict__ bsum,
                         double* __restrict__ stats) {
    if (blockIdx.x == 0 && blockIdx.y == 0 && threadIdx.x < 5) stats[threadIdx.x] = 0.0;
    const int w = blockIdx.x * 256 + threadIdx.x;
    const int chunk = blockIdx.y;
    double acc = 0.0;
    for (int k = 0; k < chunk; ++k) acc += bsum[k * WW + w];
    const int r0 = chunk * 32;
    for (int r = r0; r < r0 + 32; ++r) {
        acc += rowpref[(size_t)r * WW + w];
        rowpref[(size_t)r * WW + w] = acc;
    }
}

// Kernel D: per-box iou + fp64 reductions of {Σu, Σu², Σs, Σs²}.
__global__ void box_stats(const int* __restrict__ ssw, const double* __restrict__ C,
                          const float* __restrict__ score,
                          float* __restrict__ iou, double* __restrict__ stats) {
    const int r = blockIdx.x * 256 + threadIdx.x;
    const int* b = ssw + r * 5;
    const int x1 = b[1], y1 = b[2], x2 = b[3], y2 = b[4];
    double p22 = C[(size_t)(y2 - 1) * WW + (x2 - 1)];
    double p12 = (y1 > 0) ? C[(size_t)(y1 - 1) * WW + (x2 - 1)] : 0.0;
    double p21 = (x1 > 0) ? C[(size_t)(y2 - 1) * WW + (x1 - 1)] : 0.0;
    double p11 = (y1 > 0 && x1 > 0) ? C[(size_t)(y1 - 1) * WW + (x1 - 1)] : 0.0;
    double sums = p22 - p12 - p21 + p11;
    double area = (double)((y2 - y1) * (x2 - x1));
    double u = sums / area;
    iou[r] = (float)u;
    double s = (double)score[r];

    double v0 = u, v1 = u * u, v2 = s, v3 = s * s;
    #pragma unroll
    for (int off = 32; off; off >>= 1) {
        v0 += __shfl_down(v0, off, 64);
        v1 += __shfl_down(v1, off, 64);
        v2 += __shfl_down(v2, off, 64);
        v3 += __shfl_down(v3, off, 64);
    }
    if ((threadIdx.x & 63) == 0) {
        atomicAdd(&stats[0], v0);
        atomicAdd(&stats[1], v1);
        atomicAdd(&stats[2], v2);
        atomicAdd(&stats[3], v3);
    }
}

// Kernel E: S_ab = Σ_ij sqrt((du²+ε)(ds²+ε)).
// Grid (8192/1024, 8192/128) = (8, 64), block 256, 4 i per thread.
#define JTILE 128
__global__ void pair_prod(const float* __restrict__ iou, const float* __restrict__ score,
                          double* __restrict__ stats) {
    __shared__ float ju[JTILE];
    __shared__ float js[JTILE];
    const int t = threadIdx.x;
    const int j0 = blockIdx.y * JTILE;
    if (t < JTILE) ju[t] = iou[j0 + t];
    else if (t < 2 * JTILE) js[t - JTILE] = score[j0 + t - JTILE];

    const int i0 = blockIdx.x * 1024 + t;
    float iu[4], is[4];
    #pragma unroll
    for (int k = 0; k < 4; ++k) {
        iu[k] = iou[i0 + 256 * k];
        is[k] = score[i0 + 256 * k];
    }
    __syncthreads();

    float acc[4] = {0.f, 0.f, 0.f, 0.f};
    #pragma unroll 8
    for (int j = 0; j < JTILE; ++j) {
        const float uj = ju[j];
        const float sj = js[j];
        #pragma unroll
        for (int k = 0; k < 4; ++k) {
            float du = iu[k] - uj;
            float p  = fmaf(du, du, EPSF);
            float ds = is[k] - sj;
            float q  = fmaf(ds, ds, EPSF);
            acc[k] += __builtin_amdgcn_sqrtf(p * q);
        }
    }
    double v = (double)((acc[0] + acc[1]) + (acc[2] + acc[3]));
    #pragma unroll
    for (int off = 32; off; off >>= 1) v += __shfl_down(v, off, 64);
    __shared__ double wred[4];
    const int lane = t & 63, wid = t >> 6;
    if (lane == 0) wred[wid] = v;
    __syncthreads();
    if (t == 0) atomicAdd(&stats[4], wred[0] + wred[1] + wred[2] + wred[3]);
}

// Kernel F: loss = [2RΣu² − 2(Σu)² + 2RΣs² − 2(Σs)² + 2R²ε − 2 S_ab] / R²
__global__ void finalize(const double* __restrict__ stats, float* __restrict__ out) {
    const double R = (double)RR;
    double Su = stats[0], Su2 = stats[1], Ss = stats[2], Ss2 = stats[3], Sab = stats[4];
    double lossR2 = 2.0 * R * Su2 - 2.0 * Su * Su
                  + 2.0 * R * Ss2 - 2.0 * Ss * Ss
                  + 2.0 * R * R * EPSD
                  - 2.0 * Sab;
    out[0] = (float)(lossR2 / (R * R));
}

extern "C" void kernel_launch(void* const* d_in, const int* in_sizes, int n_in,
                              void* d_out, int out_size, void* d_ws, size_t ws_size,
                              hipStream_t stream) {
    const int*   ssw   = (const int*)d_in[0];
    const float* seg   = (const float*)d_in[1];
    const float* score = (const float*)d_in[2];

    double* rowpref = (double*)d_ws;
    double* bsum    = (double*)((char*)d_ws + OFF_BSUM);
    float*  iou     = (float*)((char*)d_ws + OFF_IOU);
    double* stats   = (double*)((char*)d_ws + OFF_STAT);

    row_scan<<<HH, 256, 0, stream>>>(seg, rowpref);
    col_partial<<<dim3(4, 32), 256, 0, stream>>>(rowpref, bsum);
    col_scan<<<dim3(4, 32), 256, 0, stream>>>(rowpref, bsum, stats);
    box_stats<<<RR / 256, 256, 0, stream>>>(ssw, rowpref, score, iou, stats);
    pair_prod<<<dim3(RR / 1024, RR / JTILE), 256, 0, stream>>>(iou, score, stats);
    finalize<<<1, 1, 0, stream>>>(stats, (float*)d_out);
}